// Round 8
// baseline (8164.010 us; speedup 1.0000x reference)
//
#include <hip/hip_runtime.h>

typedef _Float16 f16;
typedef _Float16 f16x8 __attribute__((ext_vector_type(8)));
typedef _Float16 f16x4 __attribute__((ext_vector_type(4)));
typedef float f32x4 __attribute__((ext_vector_type(4)));

#define T_TOT 2048
#define BATCH 64
#define HID 256
#define G3 768
#define WS 32
#define NWIN 64
#define NRING 4

#define NLOG2E -1.44269504088896f   // -log2(e): sigmoid pre-scale
#define P2LOG2E 2.88539008177793f   // +2*log2(e): tanh pre-scale

// flags (monotone single-writer counters), zero-initialized:
#define F_YPROG(lg)   (lg)                    // scan l: y windows produced
#define F_IPCONS(lg)  (24 + (lg))             // scan l: ip windows consumed
#define F_IPP(lg,q)   (48 + (lg)*4 + (q))     // worker q of layer l: ip produced
#define F_YC(lg,q)    (144 + (lg)*4 + (q))    // worker q of layer l+1: y consumed

__device__ __forceinline__ float fexp2(float x) { return __builtin_amdgcn_exp2f(x); }
__device__ __forceinline__ float frcp(float x) { return __builtin_amdgcn_rcpf(x); }

__device__ __forceinline__ void st_rel(int* p, int v) {
    __hip_atomic_store(p, v, __ATOMIC_RELEASE, __HIP_MEMORY_SCOPE_AGENT);
}
__device__ __forceinline__ int ld_rlx(int* p) {
    return __hip_atomic_load(p, __ATOMIC_RELAXED, __HIP_MEMORY_SCOPE_AGENT);
}
__device__ __forceinline__ void wait_ge(int* f, int target, int tid) {
    if (tid == 0) {
        while (ld_rlx(f) < target) __builtin_amdgcn_s_sleep(4);
        __builtin_amdgcn_fence(__ATOMIC_ACQUIRE, "agent");
    }
    __syncthreads();
}
__device__ __forceinline__ void wait4_ge(int* f, int target, int tid) {
    if (tid == 0) {
        #pragma unroll
        for (int q = 0; q < 4; ++q)
            while (ld_rlx(f + q) < target) __builtin_amdgcn_s_sleep(4);
        __builtin_amdgcn_fence(__ATOMIC_ACQUIRE, "agent");
    }
    __syncthreads();
}
// barrier draining ONLY LDS ops; global loads/stores stay in flight
__device__ __forceinline__ void bar_lgkm() {
    asm volatile("s_waitcnt lgkmcnt(0)\n\ts_barrier" ::: "memory");
}

__global__ void cvt_f16(const float* __restrict__ s, f16* __restrict__ d, int n) {
    int i = (blockIdx.x * 256 + threadIdx.x) * 4;
    if (i + 3 < n) {
        f32x4 v = *(const f32x4*)(s + i);
        f16x4 o = { (f16)v[0], (f16)v[1], (f16)v[2], (f16)v[3] };
        *(f16x4*)(d + i) = o;
    }
}

// W_hh with gate pre-scale: rows<512 (r,z) * -log2e; rows>=512 (n) * 2log2e
__global__ void cvt_whh(const float* __restrict__ s, f16* __restrict__ d, int n) {
    int i = (blockIdx.x * 256 + threadIdx.x) * 4;
    if (i + 3 < n) {
        int row = (i >> 8) % G3;
        float sc = (row < 512) ? NLOG2E : P2LOG2E;
        f32x4 v = *(const f32x4*)(s + i);
        f16x4 o = { (f16)(v[0] * sc), (f16)(v[1] * sc), (f16)(v[2] * sc), (f16)(v[3] * sc) };
        *(f16x4*)(d + i) = o;
    }
}

// biasc[l][g] = scale_g * (b_ih + b_hh for r,z ; b_ih only for n)
__global__ void bias_prep(const float* __restrict__ bi, const float* __restrict__ bh,
                          float* __restrict__ o) {
    int i = blockIdx.x * 256 + threadIdx.x;
    if (i < 6 * G3) {
        int g = i % G3;
        float sc = (g < 512) ? NLOG2E : P2LOG2E;
        o[i] = sc * (bi[i] + (g < 512 ? bh[i] : 0.0f));
    }
}

// bhns[l][j] = 2log2e * b_hh[l][512+j]
__global__ void bhn_prep(const float* __restrict__ bh, float* __restrict__ o) {
    int l = blockIdx.x, j = threadIdx.x;
    o[l * 256 + j] = P2LOG2E * bh[l * G3 + 512 + j];
}

// ---------------- scan role: one block = (layer l, batch group g of 16), 8 waves -------
// h in LDS in FRAGMENT ORDER: FR(k,b) = (k*16+b)*8 f16. Weights pre-scaled (see above):
//  r = rcp(1+exp2(accR+ipR)), z likewise, tanh = 1-2*rcp(1+exp2(ipN + r*accN)).
__device__ void scan_role(const f16* __restrict__ ipring, f16* __restrict__ yring,
                          const f16* __restrict__ whh, const float* __restrict__ bhns,
                          const float* __restrict__ h0, float* __restrict__ out,
                          int* flags, char* smem, int l, int g, int tid) {
    f16* hb = (f16*)smem;                      // double buffer [2][4096] f16 = 16 KB
    const int wv = tid >> 6, lane = tid & 63;
    const int quad = lane >> 4, b = lane & 15;
    const int gbase = 32 * wv + quad * 4;
    const int lg = l * 4 + g;
    const int kk0 = 4 * wv + (quad >> 1);      // gate-write chunk base (s adds 2)
    const int wsub = (quad & 1) * 4;           // 8B sub-offset inside chunk

    f16x8 wf[6][8];
    #pragma unroll
    for (int i = 0; i < 6; ++i) {
        const f16* wp = whh + (long)l * G3 * HID
                      + ((i >> 1) * 256 + 32 * wv + (i & 1) * 16 + b) * 256 + quad * 8;
        #pragma unroll
        for (int kf = 0; kf < 8; ++kf)
            wf[i][kf] = *(const f16x8*)(wp + kf * 32);
    }
    f32x4 bhn[2];
    bhn[0] = *(const f32x4*)(bhns + l * 256 + gbase);
    bhn[1] = *(const f32x4*)(bhns + l * 256 + gbase + 16);

    {   // h0 -> buffer 0 in FR layout
        int k = tid >> 4, bb = tid & 15;
        const float* hp = h0 + (long)(l * 64 + g * 16 + bb) * HID + k * 8;
        f32x4 v0 = *(const f32x4*)hp;
        f32x4 v1 = *(const f32x4*)(hp + 4);
        f16x8 h8 = { (f16)v0[0], (f16)v0[1], (f16)v0[2], (f16)v0[3],
                     (f16)v1[0], (f16)v1[1], (f16)v1[2], (f16)v1[3] };
        *(f16x8*)(&hb[(k * 16 + bb) * 8]) = h8;
    }
    f16x4 hp_[2];                               // lane's own h slice, register-resident
    #pragma unroll
    for (int s = 0; s < 2; ++s) {
        f32x4 v = *(const f32x4*)(h0 + (long)(l * 64 + g * 16 + b) * HID + gbase + s * 16);
        hp_[s] = (f16x4){ (f16)v[0], (f16)v[1], (f16)v[2], (f16)v[3] };
    }
    __syncthreads();

    for (int w = 0; w < NWIN; ++w) {
        if (l < 5 && w >= NRING)
            wait4_ge(flags + F_YC(lg, 0), w - NRING + 1, tid);
        wait4_ge(flags + F_IPP(lg, 0), w + 1, tid);
        const int slot = w & (NRING - 1);
        const f16* ipn = ipring + ((long)lg * NRING + slot) * 512 * G3
                       + (long)b * G3 + gbase;
        f16* yc = yring + (((long)lg * NRING + slot) * 512 + b) * HID + gbase;
        // 2-deep prefetch: A = t0, B = t1; each step reloads its set from t+2
        f16x4 prA[2], pzA[2], pnA[2], prB[2], pzB[2], pnB[2];
        #pragma unroll
        for (int s = 0; s < 2; ++s) {
            prA[s] = *(const f16x4*)(ipn + s * 16);
            pzA[s] = *(const f16x4*)(ipn + 256 + s * 16);
            pnA[s] = *(const f16x4*)(ipn + 512 + s * 16);
        }
        ipn += 16 * G3;
        #pragma unroll
        for (int s = 0; s < 2; ++s) {
            prB[s] = *(const f16x4*)(ipn + s * 16);
            pzB[s] = *(const f16x4*)(ipn + 256 + s * 16);
            pnB[s] = *(const f16x4*)(ipn + 512 + s * 16);
        }
        ipn += 16 * G3;                        // now at t2
        for (int tp = 0; tp < WS; tp += 2) {
            #pragma unroll
            for (int u = 0; u < 2; ++u) {
                const int rdo = u * 4096;       // read h(t-1) from buffer u
                const int wro = (u ^ 1) * 4096; // write h(t) to buffer u^1
                f32x4 acc[6];
                acc[0] = acc[1] = acc[2] = acc[3] = (f32x4){0.f, 0.f, 0.f, 0.f};
                acc[4] = bhn[0];                // pre-scaled b_hh_n in acc init
                acc[5] = bhn[1];
                #pragma unroll
                for (int kf = 0; kf < 8; ++kf) {
                    f16x8 hf = *(const f16x8*)(&hb[rdo + ((kf * 4 + quad) * 16 + b) * 8]);
                    #pragma unroll
                    for (int i = 0; i < 6; ++i)
                        acc[i] = __builtin_amdgcn_mfma_f32_16x16x32_f16(
                            wf[i][kf], hf, acc[i], 0, 0, 0);
                }
                f16x4* pr = u ? prB : prA;
                f16x4* pz = u ? pzB : pzA;
                f16x4* pn = u ? pnB : pnA;
                f16x4 hnew[2];
                #pragma unroll
                for (int s = 0; s < 2; ++s) {
                    #pragma unroll
                    for (int r = 0; r < 4; ++r) {
                        float rr = frcp(1.0f + fexp2(acc[s][r] + (float)pr[s][r]));
                        float zz = frcp(1.0f + fexp2(acc[2 + s][r] + (float)pz[s][r]));
                        float tt = frcp(1.0f + fexp2((float)pn[s][r] + rr * acc[4 + s][r]));
                        float nn = 1.0f - 2.0f * tt;
                        hnew[s][r] = (f16)(nn + zz * ((float)hp_[s][r] - nn));
                    }
                    hp_[s] = hnew[s];
                    *(f16x4*)(&hb[wro + ((kk0 + 2 * s) * 16 + b) * 8 + wsub]) = hnew[s];
                }
                // refill this step's prefetch set from t+2 (clamped at window end);
                // loads issue BEFORE y-store so the FIFO wait next use is loads-only
                #pragma unroll
                for (int s = 0; s < 2; ++s) {
                    pr[s] = *(const f16x4*)(ipn + s * 16);
                    pz[s] = *(const f16x4*)(ipn + 256 + s * 16);
                    pn[s] = *(const f16x4*)(ipn + 512 + s * 16);
                }
                if (tp + u + 3 < WS) ipn += 16 * G3;
                if (l < 5) {
                    *(f16x4*)(yc) = hnew[0];
                    *(f16x4*)(yc + 16) = hnew[1];
                }
                yc += 16 * HID;
                bar_lgkm();                     // LDS-only drain, 1 barrier/step
            }
        }
        __syncthreads();                        // full drain (vmcnt) before publish
        if (tid == 0) {
            st_rel(flags + F_IPCONS(lg), w + 1);
            if (l < 5) st_rel(flags + F_YPROG(lg), w + 1);
        }
    }
    {   // final h (buffer 0 after 2048 steps) -> out (f32)
        int k = tid >> 4, bb = tid & 15;
        f16x8 h8 = *(const f16x8*)(&hb[(k * 16 + bb) * 8]);
        float* op = out + (long)(l * 64 + g * 16 + bb) * HID + k * 8;
        f32x4 v0 = { (float)h8[0], (float)h8[1], (float)h8[2], (float)h8[3] };
        f32x4 v1 = { (float)h8[4], (float)h8[5], (float)h8[6], (float)h8[7] };
        *(f32x4*)op = v0;
        *(f32x4*)(op + 4) = v1;
    }
}

// -------- worker role: ip GEMM, 8 waves, one 128-row m-tile (q) per window -------------
// Epilogue applies the gate pre-scale: ip = scale_col * acc + biasc (biasc pre-scaled).
template<int K>
__device__ void worker_role(const f16* __restrict__ src, bool is_x, int g,
                            const f16* __restrict__ Wl, const float* __restrict__ bias,
                            f16* __restrict__ dstb, int* flags,
                            int lay, int lg, int plg, int q,
                            char* smem, int tid) {
    f16* As = (f16*)smem;                      // [128][K]
    const int wv = tid >> 6, lane = tid & 63;
    const int quad = lane >> 4, l16 = lane & 15;
    const int mi = wv & 3, ni = wv >> 2;
    constexpr int CPR = K / 8;

    for (int w = 0; w < NWIN; ++w) {
        if (lay > 0) wait_ge(flags + F_YPROG(plg), w + 1, tid);
        if (w >= NRING) wait_ge(flags + F_IPCONS(lg), w - NRING + 1, tid);
        const int slot = w & (NRING - 1);
        f16* dst = dstb + (long)slot * 512 * G3;
        #pragma unroll
        for (int it = 0; it < (128 * CPR) / 512; ++it) {
            int idx = it * 512 + tid;
            int row = idx / CPR, c8 = idx % CPR;
            int wr = q * 128 + row;
            long soff;
            if (is_x) soff = ((long)(w * WS + (wr >> 4)) * 64 + g * 16 + (wr & 15)) * K + c8 * 8;
            else      soff = ((long)slot * 512 + wr) * K + c8 * 8;
            f16x8 v = *(const f16x8*)(src + soff);
            *(f16x8*)(&As[row * K + (c8 ^ (row & 7)) * 8]) = v;
        }
        __syncthreads();
        for (int nt = 0; nt < 6; ++nt) {
            const int cbase = nt * 128 + ni * 64;
            f16x8 bc[4], bn[4];
            #pragma unroll
            for (int ns = 0; ns < 4; ++ns)
                bc[ns] = *(const f16x8*)(Wl + (long)(cbase + ns * 16 + l16) * K + quad * 8);
            f32x4 acc[2][4];
            #pragma unroll
            for (int i = 0; i < 2; ++i)
                #pragma unroll
                for (int j = 0; j < 4; ++j) acc[i][j] = (f32x4){0.f, 0.f, 0.f, 0.f};
            #pragma unroll
            for (int kf = 0; kf < K / 32; ++kf) {
                if (kf + 1 < K / 32) {
                    #pragma unroll
                    for (int ns = 0; ns < 4; ++ns)
                        bn[ns] = *(const f16x8*)(Wl + (long)(cbase + ns * 16 + l16) * K
                                                 + (kf + 1) * 32 + quad * 8);
                }
                f16x8 af[2];
                #pragma unroll
                for (int ms = 0; ms < 2; ++ms) {
                    int row = 32 * mi + 16 * ms + l16;
                    int c8 = (kf * 4 + quad) ^ (row & 7);
                    af[ms] = *(const f16x8*)(&As[row * K + c8 * 8]);
                }
                #pragma unroll
                for (int ms = 0; ms < 2; ++ms)
                    #pragma unroll
                    for (int ns = 0; ns < 4; ++ns)
                        acc[ms][ns] = __builtin_amdgcn_mfma_f32_16x16x32_f16(
                            af[ms], bc[ns], acc[ms][ns], 0, 0, 0);
                #pragma unroll
                for (int ns = 0; ns < 4; ++ns) bc[ns] = bn[ns];
            }
            #pragma unroll
            for (int ns = 0; ns < 4; ++ns) {
                int col = cbase + ns * 16 + l16;
                float bv = bias[col];
                float sc = (col < 512) ? NLOG2E : P2LOG2E;
                #pragma unroll
                for (int ms = 0; ms < 2; ++ms) {
                    int m = q * 128 + 32 * mi + 16 * ms + quad * 4;
                    #pragma unroll
                    for (int r = 0; r < 4; ++r)
                        dst[(long)(m + r) * G3 + col] = (f16)(acc[ms][ns][r] * sc + bv);
                }
            }
        }
        __syncthreads();                        // drains ip stores + protects As WAR
        if (tid == 0) {
            st_rel(flags + F_IPP(lg, q), w + 1);
            if (lay > 0) st_rel(flags + F_YC(plg, q), w + 1);
        }
    }
}

// XCD-affine decode: bid = xcd + 8*j, 3 lg per XCD, 5 roles (1 scan + 4 workers) per lg.
__global__ __launch_bounds__(512, 2) void gru_fused(
        const f16* __restrict__ xh, const f16* __restrict__ wih,
        const f16* __restrict__ whh, const float* __restrict__ biasc,
        const float* __restrict__ bhns, const float* __restrict__ h0,
        float* __restrict__ out, f16* __restrict__ yring, f16* __restrict__ ipring,
        int* flags) {
    __shared__ __align__(16) char smem[65536];
    const int bid = blockIdx.x, tid = threadIdx.x;
    const int x = bid & 7, j = bid >> 3;
    const int lgrp = j / 5, role = j % 5;
    const int lg = lgrp * 8 + x;                // 0..23, same-XCD as its workers
    const int l = lg >> 2, g = lg & 3;
    if (role == 0) {
        scan_role(ipring, yring, whh, bhns, h0, out, flags, smem, l, g, tid);
    } else {
        const int q = role - 1;
        const float* bias = biasc + l * G3;
        f16* dstb = ipring + (long)lg * NRING * 512 * G3;
        if (l == 0) {
            worker_role<128>(xh, true, g, wih, bias, dstb, flags,
                             0, lg, 0, q, smem, tid);
        } else {
            int plg = (l - 1) * 4 + g;
            const f16* Wl = wih + 768 * 128 + (long)(l - 1) * G3 * HID;
            const f16* src = yring + (long)plg * NRING * 512 * HID;
            worker_role<256>(src, false, g, Wl, bias, dstb, flags,
                             l, lg, plg, q, smem, tid);
        }
    }
}

extern "C" void kernel_launch(void* const* d_in, const int* in_sizes, int n_in,
                              void* d_out, int out_size, void* d_ws, size_t ws_size,
                              hipStream_t stream) {
    const float* x     = (const float*)d_in[0];   // [2048,64,128]
    const float* h0    = (const float*)d_in[1];   // [6,64,256]
    const float* w_ih0 = (const float*)d_in[2];   // [768,128]
    const float* w_ihr = (const float*)d_in[3];   // [5,768,256]
    const float* w_hh  = (const float*)d_in[4];   // [6,768,256]
    const float* b_ih  = (const float*)d_in[5];   // [6,768]
    const float* b_hh  = (const float*)d_in[6];   // [6,768]
    float* out = (float*)d_out;                   // [6,64,256]

    char* p = (char*)d_ws;
    f16* xh      = (f16*)p;   p += (long)T_TOT * BATCH * 128 * 2;        // 33.5 MB
    f16* wih     = (f16*)p;   p += (long)(768 * 128 + 5 * 768 * 256) * 2;
    f16* whh     = (f16*)p;   p += (long)6 * 768 * 256 * 2;
    float* biasc = (float*)p; p += (long)6 * G3 * 4;
    float* bhns  = (float*)p; p += (long)6 * 256 * 4;
    f16* yring   = (f16*)p;   p += (long)20 * NRING * 512 * HID * 2;     // 21 MB
    f16* ipring  = (f16*)p;   p += (long)24 * NRING * 512 * G3 * 2;      // 75.5 MB
    int* flags   = (int*)p;   p += 1024;

    hipMemsetAsync(flags, 0, 1024, stream);
    cvt_f16<<<16384, 256, 0, stream>>>(x, xh, T_TOT * BATCH * 128);
    cvt_f16<<<96, 256, 0, stream>>>(w_ih0, wih, 768 * 128);
    cvt_f16<<<960, 256, 0, stream>>>(w_ihr, wih + 768 * 128, 5 * 768 * 256);
    cvt_whh<<<1152, 256, 0, stream>>>(w_hh, whh, 6 * 768 * 256);
    bias_prep<<<18, 256, 0, stream>>>(b_ih, b_hh, biasc);
    bhn_prep<<<6, 256, 0, stream>>>(b_hh, bhns);

    gru_fused<<<120, 512, 0, stream>>>(xh, wih, whh, biasc, bhns, h0, out,
                                       yring, ipring, flags);
}

// Round 9
// 5181.743 us; speedup vs baseline: 1.5755x; 1.5755x over previous
//
#include <hip/hip_runtime.h>

typedef _Float16 f16;
typedef _Float16 f16x8 __attribute__((ext_vector_type(8)));
typedef _Float16 f16x4 __attribute__((ext_vector_type(4)));
typedef float f32x4 __attribute__((ext_vector_type(4)));

#define T_TOT 2048
#define BATCH 64
#define HID 256
#define G3 768
#define WS 32
#define NWIN 64
#define NRING 4
#define IPT 12288                   // f16 per timestep per lg: 3 gates x 256 j x 16 b
#define IPSLOT (WS * IPT)           // 393216 f16 per ring slot

#define NLOG2E -1.44269504088896f   // -log2(e): sigmoid pre-scale
#define P2LOG2E 2.88539008177793f   // +2*log2(e): tanh pre-scale

// flags (monotone single-writer counters), zero-initialized:
#define F_YPROG(lg)   (lg)                    // scan l: y windows produced
#define F_IPCONS(lg)  (24 + (lg))             // scan l: ip windows consumed
#define F_IPP(lg,q)   (48 + (lg)*4 + (q))     // worker q of layer l: ip produced
#define F_YC(lg,q)    (144 + (lg)*4 + (q))    // worker q of layer l+1: y consumed

__device__ __forceinline__ float fexp2(float x) { return __builtin_amdgcn_exp2f(x); }
__device__ __forceinline__ float frcp(float x) { return __builtin_amdgcn_rcpf(x); }

__device__ __forceinline__ void st_rel(int* p, int v) {
    __hip_atomic_store(p, v, __ATOMIC_RELEASE, __HIP_MEMORY_SCOPE_AGENT);
}
__device__ __forceinline__ int ld_rlx(int* p) {
    return __hip_atomic_load(p, __ATOMIC_RELAXED, __HIP_MEMORY_SCOPE_AGENT);
}
__device__ __forceinline__ void wait_ge(int* f, int target, int tid) {
    if (tid == 0) {
        while (ld_rlx(f) < target) __builtin_amdgcn_s_sleep(4);
        __builtin_amdgcn_fence(__ATOMIC_ACQUIRE, "agent");
    }
    __syncthreads();
}
__device__ __forceinline__ void wait4_ge(int* f, int target, int tid) {
    if (tid == 0) {
        #pragma unroll
        for (int q = 0; q < 4; ++q)
            while (ld_rlx(f + q) < target) __builtin_amdgcn_s_sleep(4);
        __builtin_amdgcn_fence(__ATOMIC_ACQUIRE, "agent");
    }
    __syncthreads();
}
// barrier draining ONLY LDS ops; global loads/stores stay in flight
__device__ __forceinline__ void bar_lgkm() {
    asm volatile("s_waitcnt lgkmcnt(0)\n\ts_barrier" ::: "memory");
}

__global__ void cvt_f16(const float* __restrict__ s, f16* __restrict__ d, int n) {
    int i = (blockIdx.x * 256 + threadIdx.x) * 4;
    if (i + 3 < n) {
        f32x4 v = *(const f32x4*)(s + i);
        f16x4 o = { (f16)v[0], (f16)v[1], (f16)v[2], (f16)v[3] };
        *(f16x4*)(d + i) = o;
    }
}

// W_hh with gate pre-scale: rows<512 (r,z) * -log2e; rows>=512 (n) * 2log2e
__global__ void cvt_whh(const float* __restrict__ s, f16* __restrict__ d, int n) {
    int i = (blockIdx.x * 256 + threadIdx.x) * 4;
    if (i + 3 < n) {
        int row = (i >> 8) % G3;
        float sc = (row < 512) ? NLOG2E : P2LOG2E;
        f32x4 v = *(const f32x4*)(s + i);
        f16x4 o = { (f16)(v[0] * sc), (f16)(v[1] * sc), (f16)(v[2] * sc), (f16)(v[3] * sc) };
        *(f16x4*)(d + i) = o;
    }
}

// biasc[l][g] = scale_g * (b_ih + b_hh for r,z ; b_ih only for n)
__global__ void bias_prep(const float* __restrict__ bi, const float* __restrict__ bh,
                          float* __restrict__ o) {
    int i = blockIdx.x * 256 + threadIdx.x;
    if (i < 6 * G3) {
        int g = i % G3;
        float sc = (g < 512) ? NLOG2E : P2LOG2E;
        o[i] = sc * (bi[i] + (g < 512 ? bh[i] : 0.0f));
    }
}

// bhns[l][j] = 2log2e * b_hh[l][512+j]
__global__ void bhn_prep(const float* __restrict__ bh, float* __restrict__ o) {
    int l = blockIdx.x, j = threadIdx.x;
    o[l * 256 + j] = P2LOG2E * bh[l * G3 + 512 + j];
}

// ---------------- scan role: one block = (layer l, batch group g of 16), 8 waves -------
// h in LDS in FRAGMENT ORDER: FR(k,b) = (k*16+b)*8 f16.
// ip in LANE-FRAGMENT ORDER: ip2[t][gate][wv][quad][b][8] -> each lane reads one f16x8
// (16B) per gate, wave-contiguous 1KB per load. Values: idx s*4+r for rows gbase+16s+r.
__device__ void scan_role(const f16* __restrict__ ipring, f16* __restrict__ yring,
                          const f16* __restrict__ whh, const float* __restrict__ bhns,
                          const float* __restrict__ h0, float* __restrict__ out,
                          int* flags, char* smem, int l, int g, int tid) {
    f16* hb = (f16*)smem;                      // double buffer [2][4096] f16 = 16 KB
    const int wv = tid >> 6, lane = tid & 63;
    const int quad = lane >> 4, b = lane & 15;
    const int gbase = 32 * wv + quad * 4;
    const int lg = l * 4 + g;
    const int kk0 = 4 * wv + (quad >> 1);      // gate-write chunk base (s adds 2)
    const int wsub = (quad & 1) * 4;           // 8B sub-offset inside chunk

    f16x8 wf[6][8];
    #pragma unroll
    for (int i = 0; i < 6; ++i) {
        const f16* wp = whh + (long)l * G3 * HID
                      + ((i >> 1) * 256 + 32 * wv + (i & 1) * 16 + b) * 256 + quad * 8;
        #pragma unroll
        for (int kf = 0; kf < 8; ++kf)
            wf[i][kf] = *(const f16x8*)(wp + kf * 32);
    }
    f32x4 bhn[2];
    bhn[0] = *(const f32x4*)(bhns + l * 256 + gbase);
    bhn[1] = *(const f32x4*)(bhns + l * 256 + gbase + 16);

    {   // h0 -> buffer 0 in FR layout
        int k = tid >> 4, bb = tid & 15;
        const float* hp = h0 + (long)(l * 64 + g * 16 + bb) * HID + k * 8;
        f32x4 v0 = *(const f32x4*)hp;
        f32x4 v1 = *(const f32x4*)(hp + 4);
        f16x8 h8 = { (f16)v0[0], (f16)v0[1], (f16)v0[2], (f16)v0[3],
                     (f16)v1[0], (f16)v1[1], (f16)v1[2], (f16)v1[3] };
        *(f16x8*)(&hb[(k * 16 + bb) * 8]) = h8;
    }
    f16x4 hp_[2];                               // lane's own h slice, register-resident
    #pragma unroll
    for (int s = 0; s < 2; ++s) {
        f32x4 v = *(const f32x4*)(h0 + (long)(l * 64 + g * 16 + b) * HID + gbase + s * 16);
        hp_[s] = (f16x4){ (f16)v[0], (f16)v[1], (f16)v[2], (f16)v[3] };
    }
    __syncthreads();

    const int lane_off = (wv * 4 + quad) * 128 + b * 8;   // lane's slot inside a gate blk
    for (int w = 0; w < NWIN; ++w) {
        if (l < 5 && w >= NRING)
            wait4_ge(flags + F_YC(lg, 0), w - NRING + 1, tid);
        wait4_ge(flags + F_IPP(lg, 0), w + 1, tid);
        const int slot = w & (NRING - 1);
        const f16* ipt = ipring + (long)(lg * NRING + slot) * IPSLOT + lane_off;
        f16* yc = yring + (((long)lg * NRING + slot) * 512 + b) * HID + gbase;
        f16x8 p0 = *(const f16x8*)(ipt);              // prime t=0: r, z, n chunks
        f16x8 p1 = *(const f16x8*)(ipt + 4096);
        f16x8 p2 = *(const f16x8*)(ipt + 8192);
        for (int tp = 0; tp < WS; tp += 2) {
            #pragma unroll
            for (int u = 0; u < 2; ++u) {
                const int rdo = u * 4096;       // read h(t-1) from buffer u
                const int wro = (u ^ 1) * 4096; // write h(t) to buffer u^1
                f32x4 acc[6];
                acc[0] = acc[1] = acc[2] = acc[3] = (f32x4){0.f, 0.f, 0.f, 0.f};
                acc[4] = bhn[0];                // pre-scaled b_hh_n in acc init
                acc[5] = bhn[1];
                #pragma unroll
                for (int kf = 0; kf < 8; ++kf) {
                    f16x8 hf = *(const f16x8*)(&hb[rdo + ((kf * 4 + quad) * 16 + b) * 8]);
                    #pragma unroll
                    for (int i = 0; i < 6; ++i)
                        acc[i] = __builtin_amdgcn_mfma_f32_16x16x32_f16(
                            wf[i][kf], hf, acc[i], 0, 0, 0);
                }
                f16x4 hnew[2];
                #pragma unroll
                for (int s = 0; s < 2; ++s) {
                    #pragma unroll
                    for (int r = 0; r < 4; ++r) {
                        float rr = frcp(1.0f + fexp2(acc[s][r] + (float)p0[s * 4 + r]));
                        float zz = frcp(1.0f + fexp2(acc[2 + s][r] + (float)p1[s * 4 + r]));
                        float tt = frcp(1.0f + fexp2((float)p2[s * 4 + r] + rr * acc[4 + s][r]));
                        float nn = 1.0f - 2.0f * tt;
                        hnew[s][r] = (f16)(nn + zz * ((float)hp_[s][r] - nn));
                    }
                    hp_[s] = hnew[s];
                    *(f16x4*)(&hb[wro + ((kk0 + 2 * s) * 16 + b) * 8 + wsub]) = hnew[s];
                }
                // prefetch t+1 (clamped); loads issue BEFORE y-store (vmcnt FIFO)
                if (tp + u + 1 < WS) ipt += IPT;
                p0 = *(const f16x8*)(ipt);
                p1 = *(const f16x8*)(ipt + 4096);
                p2 = *(const f16x8*)(ipt + 8192);
                if (l < 5) {
                    *(f16x4*)(yc) = hnew[0];
                    *(f16x4*)(yc + 16) = hnew[1];
                }
                yc += 16 * HID;
                bar_lgkm();                     // LDS-only drain, 1 barrier/step
            }
        }
        __syncthreads();                        // full drain (vmcnt) before publish
        if (tid == 0) {
            st_rel(flags + F_IPCONS(lg), w + 1);
            if (l < 5) st_rel(flags + F_YPROG(lg), w + 1);
        }
    }
    {   // final h (buffer 0 after 2048 steps) -> out (f32)
        int k = tid >> 4, bb = tid & 15;
        f16x8 h8 = *(const f16x8*)(&hb[(k * 16 + bb) * 8]);
        float* op = out + (long)(l * 64 + g * 16 + bb) * HID + k * 8;
        f32x4 v0 = { (float)h8[0], (float)h8[1], (float)h8[2], (float)h8[3] };
        f32x4 v1 = { (float)h8[4], (float)h8[5], (float)h8[6], (float)h8[7] };
        *(f32x4*)op = v0;
        *(f32x4*)(op + 4) = v1;
    }
}

// -------- worker role: ip GEMM, 8 waves, one 128-row m-tile (q) per window -------------
// Epilogue: pre-scale and scatter into the lane-fragment ip layout (see scan_role).
// Window row m = t2*16 + b; for fixed (ms,ns): t2 = q*8+2*mi+ms, b = quad*4+r.
template<int K>
__device__ void worker_role(const f16* __restrict__ src, bool is_x, int g,
                            const f16* __restrict__ Wl, const float* __restrict__ bias,
                            f16* __restrict__ dstb, int* flags,
                            int lay, int lg, int plg, int q,
                            char* smem, int tid) {
    f16* As = (f16*)smem;                      // [128][K]
    const int wv = tid >> 6, lane = tid & 63;
    const int quad = lane >> 4, l16 = lane & 15;
    const int mi = wv & 3, ni = wv >> 2;
    constexpr int CPR = K / 8;

    for (int w = 0; w < NWIN; ++w) {
        if (lay > 0) wait_ge(flags + F_YPROG(plg), w + 1, tid);
        if (w >= NRING) wait_ge(flags + F_IPCONS(lg), w - NRING + 1, tid);
        const int slot = w & (NRING - 1);
        f16* dst = dstb + (long)slot * IPSLOT;
        #pragma unroll
        for (int it = 0; it < (128 * CPR) / 512; ++it) {
            int idx = it * 512 + tid;
            int row = idx / CPR, c8 = idx % CPR;
            int wr = q * 128 + row;
            long soff;
            if (is_x) soff = ((long)(w * WS + (wr >> 4)) * 64 + g * 16 + (wr & 15)) * K + c8 * 8;
            else      soff = ((long)slot * 512 + wr) * K + c8 * 8;
            f16x8 v = *(const f16x8*)(src + soff);
            *(f16x8*)(&As[row * K + (c8 ^ (row & 7)) * 8]) = v;
        }
        __syncthreads();
        for (int nt = 0; nt < 6; ++nt) {
            const int cbase = nt * 128 + ni * 64;
            f16x8 bc[4], bn[4];
            #pragma unroll
            for (int ns = 0; ns < 4; ++ns)
                bc[ns] = *(const f16x8*)(Wl + (long)(cbase + ns * 16 + l16) * K + quad * 8);
            f32x4 acc[2][4];
            #pragma unroll
            for (int i = 0; i < 2; ++i)
                #pragma unroll
                for (int j = 0; j < 4; ++j) acc[i][j] = (f32x4){0.f, 0.f, 0.f, 0.f};
            #pragma unroll
            for (int kf = 0; kf < K / 32; ++kf) {
                if (kf + 1 < K / 32) {
                    #pragma unroll
                    for (int ns = 0; ns < 4; ++ns)
                        bn[ns] = *(const f16x8*)(Wl + (long)(cbase + ns * 16 + l16) * K
                                                 + (kf + 1) * 32 + quad * 8);
                }
                f16x8 af[2];
                #pragma unroll
                for (int ms = 0; ms < 2; ++ms) {
                    int row = 32 * mi + 16 * ms + l16;
                    int c8 = (kf * 4 + quad) ^ (row & 7);
                    af[ms] = *(const f16x8*)(&As[row * K + c8 * 8]);
                }
                #pragma unroll
                for (int ms = 0; ms < 2; ++ms)
                    #pragma unroll
                    for (int ns = 0; ns < 4; ++ns)
                        acc[ms][ns] = __builtin_amdgcn_mfma_f32_16x16x32_f16(
                            af[ms], bc[ns], acc[ms][ns], 0, 0, 0);
                #pragma unroll
                for (int ns = 0; ns < 4; ++ns) bc[ns] = bn[ns];
            }
            #pragma unroll
            for (int ns = 0; ns < 4; ++ns) {
                int col = cbase + ns * 16 + l16;
                float bv = bias[col];
                float sc = (col < 512) ? NLOG2E : P2LOG2E;
                // decompose col -> (gate, wv2, s2, quad2, r2) for fragment layout
                int gate = col >> 8, j = col & 255;
                int wv2 = j >> 5, rem = j & 31;
                int s2 = rem >> 4, q2 = (rem & 15) >> 2, r2 = rem & 3;
                #pragma unroll
                for (int ms = 0; ms < 2; ++ms) {
                    int t2 = q * 8 + 2 * mi + ms;
                    f16* dp = dst + t2 * IPT + ((gate * 8 + wv2) * 4 + q2) * 128
                            + s2 * 4 + r2;
                    #pragma unroll
                    for (int r = 0; r < 4; ++r)
                        dp[(quad * 4 + r) * 8] = (f16)(acc[ms][ns][r] * sc + bv);
                }
            }
        }
        __syncthreads();                        // drains ip stores + protects As WAR
        if (tid == 0) {
            st_rel(flags + F_IPP(lg, q), w + 1);
            if (lay > 0) st_rel(flags + F_YC(plg, q), w + 1);
        }
    }
}

// XCD-affine decode: bid = xcd + 8*j, 3 lg per XCD, 5 roles (1 scan + 4 workers) per lg.
__global__ __launch_bounds__(512, 2) void gru_fused(
        const f16* __restrict__ xh, const f16* __restrict__ wih,
        const f16* __restrict__ whh, const float* __restrict__ biasc,
        const float* __restrict__ bhns, const float* __restrict__ h0,
        float* __restrict__ out, f16* __restrict__ yring, f16* __restrict__ ipring,
        int* flags) {
    __shared__ __align__(16) char smem[65536];
    const int bid = blockIdx.x, tid = threadIdx.x;
    const int x = bid & 7, j = bid >> 3;
    const int lgrp = j / 5, role = j % 5;
    const int lg = lgrp * 8 + x;                // 0..23, same-XCD as its workers
    const int l = lg >> 2, g = lg & 3;
    if (role == 0) {
        scan_role(ipring, yring, whh, bhns, h0, out, flags, smem, l, g, tid);
    } else {
        const int q = role - 1;
        const float* bias = biasc + l * G3;
        f16* dstb = ipring + (long)lg * NRING * IPSLOT;
        if (l == 0) {
            worker_role<128>(xh, true, g, wih, bias, dstb, flags,
                             0, lg, 0, q, smem, tid);
        } else {
            int plg = (l - 1) * 4 + g;
            const f16* Wl = wih + 768 * 128 + (long)(l - 1) * G3 * HID;
            const f16* src = yring + (long)plg * NRING * 512 * HID;
            worker_role<256>(src, false, g, Wl, bias, dstb, flags,
                             l, lg, plg, q, smem, tid);
        }
    }
}

extern "C" void kernel_launch(void* const* d_in, const int* in_sizes, int n_in,
                              void* d_out, int out_size, void* d_ws, size_t ws_size,
                              hipStream_t stream) {
    const float* x     = (const float*)d_in[0];   // [2048,64,128]
    const float* h0    = (const float*)d_in[1];   // [6,64,256]
    const float* w_ih0 = (const float*)d_in[2];   // [768,128]
    const float* w_ihr = (const float*)d_in[3];   // [5,768,256]
    const float* w_hh  = (const float*)d_in[4];   // [6,768,256]
    const float* b_ih  = (const float*)d_in[5];   // [6,768]
    const float* b_hh  = (const float*)d_in[6];   // [6,768]
    float* out = (float*)d_out;                   // [6,64,256]

    char* p = (char*)d_ws;
    f16* xh      = (f16*)p;   p += (long)T_TOT * BATCH * 128 * 2;        // 33.5 MB
    f16* wih     = (f16*)p;   p += (long)(768 * 128 + 5 * 768 * 256) * 2;
    f16* whh     = (f16*)p;   p += (long)6 * 768 * 256 * 2;
    float* biasc = (float*)p; p += (long)6 * G3 * 4;
    float* bhns  = (float*)p; p += (long)6 * 256 * 4;
    f16* yring   = (f16*)p;   p += (long)20 * NRING * 512 * HID * 2;     // 21 MB
    f16* ipring  = (f16*)p;   p += (long)24 * NRING * IPSLOT * 2;        // 75.5 MB
    int* flags   = (int*)p;   p += 1024;

    hipMemsetAsync(flags, 0, 1024, stream);
    cvt_f16<<<16384, 256, 0, stream>>>(x, xh, T_TOT * BATCH * 128);
    cvt_f16<<<96, 256, 0, stream>>>(w_ih0, wih, 768 * 128);
    cvt_f16<<<960, 256, 0, stream>>>(w_ihr, wih + 768 * 128, 5 * 768 * 256);
    cvt_whh<<<1152, 256, 0, stream>>>(w_hh, whh, 6 * 768 * 256);
    bias_prep<<<18, 256, 0, stream>>>(b_ih, b_hh, biasc);
    bhn_prep<<<6, 256, 0, stream>>>(b_hh, bhns);

    gru_fused<<<120, 512, 0, stream>>>(xh, wih, whh, biasc, bhns, h0, out,
                                       yring, ipring, flags);
}